// Round 2
// baseline (1251.154 us; speedup 1.0000x reference)
//
#include <hip/hip_runtime.h>
#include <hip/hip_bf16.h>

typedef unsigned short bf16_t;
typedef __bf16 bf16x8 __attribute__((ext_vector_type(8)));
typedef float f32x4 __attribute__((ext_vector_type(4)));

__device__ __forceinline__ unsigned short f2bf(float x){
  union { __hip_bfloat16 h; unsigned short u; } c;
  c.h = __float2bfloat16(x);
  return c.u;
}
__device__ __forceinline__ float bf2f(bf16_t u){
  union { unsigned short u; __hip_bfloat16 h; } c;
  c.u = u;
  return __bfloat162float(c.h);
}

#define GL2L(g, l) __builtin_amdgcn_global_load_lds( \
    (const __attribute__((address_space(1))) unsigned int*)(g), \
    (__attribute__((address_space(3))) unsigned int*)(l), 16, 0, 0)

// ---------------------------------------------------------------------------
// bf16 MFMA GEMM, 128x128 tile, BK=32, 4 waves (2x2), 4x4 frags of
// v_mfma_f32_16x16x32_bf16. Bt is [N][K] row-major.
// MAP=0: blockIdx=(col, row, ksplit)  -> id%8 = col%8 (B-panel XCD colocation;
//        launch with colTiles % 8 == 0)
// MAP=1: blockIdx=(ksplit, col, row)  -> id%8 = ksplit (split-K XCD streams)
// ACT: 0 f32 store | 1 sigmoid f32 store | 2 RZ epilogue | 3 GRU-h epilogue |
//      4 bf16 store
// ---------------------------------------------------------------------------
template<int ACT, int MAP>
__global__ __launch_bounds__(256)
void gemm_bf16(const bf16_t* __restrict__ A, int lda,
               const bf16_t* __restrict__ Bt, int ldb,
               float* __restrict__ C, int ldc, size_t csplit,
               const float* __restrict__ bias,
               int M, int N, int K, int Kchunk,
               const float* __restrict__ zbuf,
               float* __restrict__ propio,
               bf16_t* __restrict__ xn)
{
  __shared__ __align__(16) bf16_t As[128*32];
  __shared__ __align__(16) bf16_t Bs[128*32];
  const int tid = threadIdx.x;
  const int w = tid >> 6, lane = tid & 63;
  const int wm = w >> 1, wn = w & 1;
  const int lr = lane & 15, kq = lane >> 4;
  int bcol, brow, bks;
  if (MAP == 0) { bcol = blockIdx.x; brow = blockIdx.y; bks = blockIdx.z; }
  else          { bks = blockIdx.x;  bcol = blockIdx.y; brow = blockIdx.z; }
  const int gm0 = brow * 128, gn0 = bcol * 128;
  const int k0 = bks * Kchunk;
  const int kend = min(k0 + Kchunk, K);

  // staging: wave w stages rows [w*32, w*32+32), lane l -> row chunk + l/4,
  // kcol (l%4)*8
  const int srow = lane >> 2;
  const int scol = (lane & 3) << 3;
  const int am0 = min(gm0 + w*32 + srow,      M-1);
  const int am1 = min(gm0 + w*32 + 16 + srow, M-1);
  const int bn0 = min(gn0 + w*32 + srow,      N-1);
  const int bn1 = min(gn0 + w*32 + 16 + srow, N-1);
  const bf16_t* Ag0 = A  + (size_t)am0*lda + scol;
  const bf16_t* Ag1 = A  + (size_t)am1*lda + scol;
  const bf16_t* Bg0 = Bt + (size_t)bn0*ldb + scol;
  const bf16_t* Bg1 = Bt + (size_t)bn1*ldb + scol;
  char* Al0 = (char*)As + w*2048;
  char* Al1 = (char*)As + w*2048 + 1024;
  char* Bl0 = (char*)Bs + w*2048;
  char* Bl1 = (char*)Bs + w*2048 + 1024;

  f32x4 acc[4][4] = {};

  for (int k = k0; k < kend; k += 32) {
    GL2L(Ag0 + k, Al0);
    GL2L(Ag1 + k, Al1);
    GL2L(Bg0 + k, Bl0);
    GL2L(Bg1 + k, Bl1);
    __syncthreads();
    bf16x8 af[4], bfr[4];
#pragma unroll
    for (int mi = 0; mi < 4; mi++)
      af[mi] = *(const bf16x8*)((const char*)As + ((wm*64 + mi*16 + lr) << 6) + (kq << 4));
#pragma unroll
    for (int ni = 0; ni < 4; ni++)
      bfr[ni] = *(const bf16x8*)((const char*)Bs + ((wn*64 + ni*16 + lr) << 6) + (kq << 4));
#pragma unroll
    for (int mi = 0; mi < 4; mi++)
#pragma unroll
      for (int ni = 0; ni < 4; ni++)
        acc[mi][ni] = __builtin_amdgcn_mfma_f32_16x16x32_bf16(af[mi], bfr[ni], acc[mi][ni], 0, 0, 0);
    __syncthreads();
  }

  // epilogue: D row = kq*4 + i, col = lane&15 per 16x16 frag
#pragma unroll
  for (int mi = 0; mi < 4; mi++) {
#pragma unroll
    for (int ni = 0; ni < 4; ni++) {
      const int col = gn0 + wn*64 + ni*16 + lr;
      const float bv = bias ? bias[col] : 0.f;
#pragma unroll
      for (int i = 0; i < 4; i++) {
        const int row = gm0 + wm*64 + mi*16 + kq*4 + i;
        if (row < M) {
          float v = acc[mi][ni][i] + bv;
          if (ACT == 1) {
            v = 1.f / (1.f + __expf(-v));
            C[(size_t)row*ldc + col] = v;
          } else if (ACT == 2) {
            // [r|z]: r -> Xh right half as bf16(r*prop); z -> Zbuf compact
            v = 1.f / (1.f + __expf(-v));
            if (col < 1024) {
              const float pp = propio[(size_t)row*1024 + col];
              xn[(size_t)row*2048 + 1024 + col] = f2bf(v * pp);
            } else {
              C[(size_t)row*ldc + (col - 1024)] = v;   // ldc = 1024
            }
          } else if (ACT == 3) {
            v = tanhf(v);                              // h_hat
            const float z  = zbuf[(size_t)row*1024 + col];
            const float pp = propio[(size_t)row*1024 + col];
            const float pn = (1.f - z)*pp + z*v;       // GRU update
            propio[(size_t)row*1024 + col] = pn;
            xn[(size_t)row*2048 + 1024 + col] = f2bf(pn);
          } else if (ACT == 4) {
            ((bf16_t*)C)[(size_t)row*ldc + col] = f2bf(v);
          } else {
            C[(size_t)bks*csplit + (size_t)row*ldc + col] = v;
          }
        }
      }
    }
  }
}

// sum split-K partials, add bias, write prop f32 + X right half bf16
__global__ void reduce_compress(const float* __restrict__ part, const float* __restrict__ bias,
                                float* __restrict__ prop, bf16_t* __restrict__ xr)
{
  const int idx = blockIdx.x*256 + threadIdx.x;   // < 921600
  const int m = idx >> 10, d = idx & 1023;
  float v = bias[d];
#pragma unroll
  for (int z = 0; z < 8; z++) v += part[(size_t)z*921600 + idx];
  prop[idx] = v;
  xr[(size_t)m*2048 + 1024 + d] = f2bf(v);
}

// u_row[e][h] = sum_d W_edge[e][h][d]*W_att[e][d]; u_col with W_att[e][1024+d]
__global__ void compute_u(const float* __restrict__ We, const float* __restrict__ Wa,
                          float* __restrict__ u_row, float* __restrict__ u_col)
{
  const int w = threadIdx.x >> 6, lane = threadIdx.x & 63;
  const int idx = blockIdx.x*4 + w;               // grid=1792 -> idx<7168
  const int e = idx >> 10, h = idx & 1023;
  const float* wep = We + ((size_t)e*1024 + h)*1024;
  const float* wr  = Wa + (size_t)e*2048;
  const float* wc  = wr + 1024;
  float ar = 0.f, ac = 0.f;
#pragma unroll
  for (int t = 0; t < 16; t++) {
    const float v = wep[lane + 64*t];
    ar += v*wr[lane + 64*t];
    ac += v*wc[lane + 64*t];
  }
  for (int off = 32; off; off >>= 1) { ar += __shfl_down(ar, off); ac += __shfl_down(ac, off); }
  if (lane == 0) { u_row[idx] = ar; u_col[idx] = ac; }
}

// crc[e] = b_edge[e].Wa_row[e], crc[7+e] = b_edge[e].Wa_col[e]
__global__ void crc_kernel(const float* __restrict__ be, const float* __restrict__ Wa,
                           float* __restrict__ crc)
{
  const int w = threadIdx.x >> 6, lane = threadIdx.x & 63;
  for (int idx = w; idx < 14; idx += 4) {
    const int e = idx >> 1, which = idx & 1;
    const float* bp = be + e*1024;
    const float* wp = Wa + (size_t)e*2048 + which*1024;
    float a = 0.f;
#pragma unroll
    for (int t = 0; t < 16; t++) a += bp[lane + 64*t]*wp[lane + 64*t];
    for (int off = 32; off; off >>= 1) a += __shfl_down(a, off);
    if (lane == 0) crc[which*7 + e] = a;
  }
}

// per (b,e): row[n]=prop[b,n,:].u_row[e]; col[n]=prop[b,n,:].u_col[e]
// scores[b,e,i,j] = sigmoid(row[i]+col[j]+b_att[e]+crc_row[e]+crc_col[e])
__global__ void attn_kernel(const float* __restrict__ prop, const float* __restrict__ u_row,
                            const float* __restrict__ u_col, const float* __restrict__ crc,
                            const float* __restrict__ b_att, float* __restrict__ scores)
{
  const int b = blockIdx.x, e = blockIdx.y;
  __shared__ float rowv[15], colv[15];
  const int w = threadIdx.x >> 6, lane = threadIdx.x & 63;
  const float* ur = u_row + (size_t)e*1024;
  const float* uc = u_col + (size_t)e*1024;
  for (int n = w; n < 15; n += 4) {
    const float* pr = prop + (size_t)(b*15 + n)*1024;
    float ar = 0.f, ac = 0.f;
#pragma unroll
    for (int t = 0; t < 16; t++) {
      const float pv = pr[lane + 64*t];
      ar += pv*ur[lane + 64*t];
      ac += pv*uc[lane + 64*t];
    }
    for (int off = 32; off; off >>= 1) { ar += __shfl_down(ar, off); ac += __shfl_down(ac, off); }
    if (lane == 0) { rowv[n] = ar; colv[n] = ac; }
  }
  __syncthreads();
  const float base = b_att[e] + crc[e] + crc[7 + e];
  for (int idx = threadIdx.x; idx < 225; idx += 256) {
    const int i = idx/15, j = idx - i*15;
    const float s = 1.f / (1.f + __expf(-(rowv[i] + colv[j] + base)));
    scores[((size_t)(b*7 + e)*15 + i)*15 + j] = s;
  }
}

// merged[b,i,d] = sum_e sum_j scores[b,e,i,j]*msg[b*15+j, e*1024+d]
// -> X left half AND Xh left half (bf16)
__global__ void merged_kernel(const bf16_t* __restrict__ msg, const float* __restrict__ scores,
                              bf16_t* __restrict__ X, bf16_t* __restrict__ Xh)
{
  const int b = blockIdx.x, c = blockIdx.y;   // c: 128-wide d-chunk, 8 chunks
  __shared__ float ms[15*7*128];              // [j][e][dl]
  __shared__ float sc[1575];                  // [e][i][j]
  for (int q = threadIdx.x; q < 3360; q += 256) {     // 4-wide bf16 loads
    const int idx = q*4;
    const int j = idx / 896;
    const int rem = idx - j*896;
    const int e = rem >> 7, dl = rem & 127;
    const ushort4 v = *(const ushort4*)(msg + (size_t)(b*15 + j)*7168 + e*1024 + c*128 + dl);
    ms[idx]   = bf2f(v.x);
    ms[idx+1] = bf2f(v.y);
    ms[idx+2] = bf2f(v.z);
    ms[idx+3] = bf2f(v.w);
  }
  for (int idx = threadIdx.x; idx < 1575; idx += 256)
    sc[idx] = scores[(size_t)b*1575 + idx];
  __syncthreads();
  for (int oi = threadIdx.x; oi < 1920; oi += 256) {
    const int i = oi >> 7, dl = oi & 127;
    float acc = 0.f;
#pragma unroll
    for (int e = 0; e < 7; e++)
#pragma unroll
      for (int j = 0; j < 15; j++)
        acc += sc[(e*15 + i)*15 + j] * ms[j*896 + e*128 + dl];
    const bf16_t o = f2bf(acc);
    X [(size_t)(b*15 + i)*2048 + c*128 + dl] = o;
    Xh[(size_t)(b*15 + i)*2048 + c*128 + dl] = o;
  }
}

// 64x64-tile transpose f32 -> bf16: out[c][r] = in[r][c]  (dims %64 == 0)
__global__ void transpose_k(const float* __restrict__ in, bf16_t* __restrict__ out,
                            int R, int C, int out_ld, size_t in_batch, size_t out_batch)
{
  __shared__ float t[64][65];
  in  += (size_t)blockIdx.z * in_batch;
  out += (size_t)blockIdx.z * out_batch;
  const int r0 = blockIdx.x*64, c0 = blockIdx.y*64;
  const int tc = threadIdx.x & 63, tr = threadIdx.x >> 6;
#pragma unroll
  for (int i = 0; i < 16; i++) {
    const int r = tr*16 + i;
    t[r][tc] = in[(size_t)(r0 + r)*C + c0 + tc];
  }
  __syncthreads();
#pragma unroll
  for (int i = 0; i < 16; i++) {
    const int rr = tr*16 + i;
    out[(size_t)(c0 + rr)*out_ld + r0 + tc] = f2bf(t[tc][rr]);
  }
}

__global__ void cast_f32_bf16(const float4* __restrict__ in, ushort4* __restrict__ out, int n4)
{
  int i = blockIdx.x*256 + threadIdx.x;
  const int stride = gridDim.x*256;
  for (; i < n4; i += stride) {
    const float4 v = in[i];
    out[i] = make_ushort4(f2bf(v.x), f2bf(v.y), f2bf(v.z), f2bf(v.w));
  }
}

__global__ void cat2_kernel(const float* __restrict__ a, const float* __restrict__ b,
                            float* __restrict__ o)
{
  const int i = blockIdx.x*256 + threadIdx.x;
  if (i < 1024) o[i] = a[i];
  else if (i < 2048) o[i] = b[i - 1024];
}

// final outputs from last-iteration scores
__global__ void finalize_kernel(const float* __restrict__ scores, float* __restrict__ out)
{
  const int b = blockIdx.x;   // 0..59
  __shared__ float sc[1575];
  __shared__ float act[105];
  __shared__ float asum[15];
  __shared__ float t2[7];
  for (int idx = threadIdx.x; idx < 1575; idx += 256)
    sc[idx] = scores[(size_t)b*1575 + idx];
  __syncthreads();
  for (int idx = threadIdx.x; idx < 105; idx += 256) {
    const int i = idx/7, e = idx - i*7;
    float a = 0.f;
#pragma unroll
    for (int j = 0; j < 15; j++)
      a += (1.f - sc[i*15 + j]) * sc[(e*15 + i)*15 + j];
    act[idx] = a;
    out[(size_t)b*105 + idx] = a;
  }
  for (int idx = threadIdx.x; idx < 225; idx += 256) {
    const int i = idx/15, j = idx - i*15;
    out[6660 + (size_t)b*225 + idx] = 1.f - sc[i*15 + j];
  }
  if (threadIdx.x < 15) {
    const int i = threadIdx.x;
    float s = 0.f;
#pragma unroll
    for (int j = 0; j < 15; j++) s += 1.f - sc[i*15 + j];
    asum[i] = s;
  }
  __syncthreads();
  if (threadIdx.x < 7) {
    const int e = threadIdx.x;
    float t = 0.f;
#pragma unroll
    for (int i = 0; i < 15; i++) t += act[i*7 + e]*asum[i];
    t2[e] = t;
  }
  __syncthreads();
  if (threadIdx.x == 0) {
    float mx = -1e30f;
    for (int e = 1; e < 7; e++) mx = fmaxf(mx, t2[e]);
    float s = 0.f, ex[6];
    for (int e = 1; e < 7; e++) { ex[e-1] = __expf(t2[e] - mx); s += ex[e-1]; }
    for (int e = 1; e < 7; e++) out[6300 + (size_t)b*6 + (e-1)] = ex[e-1]/s;
  }
}

extern "C" void kernel_launch(void* const* d_in, const int* in_sizes, int n_in,
                              void* d_out, int out_size, void* d_ws, size_t ws_size,
                              hipStream_t stream)
{
  const float* pose = (const float*)d_in[0];
  const float* Wc   = (const float*)d_in[1];
  const float* bc   = (const float*)d_in[2];
  const float* We   = (const float*)d_in[3];
  const float* be   = (const float*)d_in[4];
  const float* Wa   = (const float*)d_in[5];
  const float* ba   = (const float*)d_in[6];
  const float* Wr   = (const float*)d_in[7];
  const float* br   = (const float*)d_in[8];
  const float* Wz   = (const float*)d_in[9];
  const float* bz   = (const float*)d_in[10];
  const float* Wh   = (const float*)d_in[11];
  const float* bh   = (const float*)d_in[12];
  float* out = (float*)d_out;

  // ---- workspace carving ----
  char* p = (char*)d_ws;
  auto alloc = [&](size_t b) { char* r = p; p += (b + 255) & ~(size_t)255; return r; };
  bf16_t* Wedge_t = (bf16_t*)alloc(7168ull*1024*2);   // [e*1024+d][h]
  bf16_t* Wrz_t   = (bf16_t*)alloc(2048ull*2048*2);   // [n][k]
  bf16_t* Wh_t    = (bf16_t*)alloc(1024ull*2048*2);   // [n][k]
  bf16_t* X       = (bf16_t*)alloc(900ull*2048*2);    // [merged | prop] bf16
  float*  prop    = (float*) alloc(900ull*1024*4);    // f32 master state
  float*  scores  = (float*) alloc(60ull*7*15*15*4);
  float*  u_row   = (float*) alloc(7168*4);
  float*  u_col   = (float*) alloc(7168*4);
  float*  crc     = (float*) alloc(64);
  float*  brzv    = (float*) alloc(2048*4);
  // phase-union region:
  // phase1 (compress): Abf(46.08) + Wct(52.43) + partial(29.49) = 128 MB
  // phase2 (iters):    msgb(12.9) + Zbuf(3.69) + Xh(3.69)       = 20.3 MB
  char* r1 = alloc(128000000ull);
  bf16_t* Abf     = (bf16_t*)r1;
  bf16_t* Wct     = (bf16_t*)(r1 + 46080000ull);
  float*  partial = (float*) (r1 + 46080000ull + 52428800ull);
  bf16_t* msgb    = (bf16_t*)r1;
  float*  Zbuf    = (float*) (r1 + 12902400ull);
  bf16_t* Xh      = (bf16_t*)(r1 + 12902400ull + 3686400ull);

  // ---- precompute ----
  compute_u<<<1792, 256, 0, stream>>>(We, Wa, u_row, u_col);
  crc_kernel<<<1, 256, 0, stream>>>(be, Wa, crc);
  cast_f32_bf16<<<2048, 256, 0, stream>>>((const float4*)pose, (ushort4*)Abf, 23040000/4);
  transpose_k<<<dim3(400,16,1), 256, 0, stream>>>(Wc, Wct, 25600, 1024, 25600, 0, 0);
  transpose_k<<<dim3(16,16,7),  256, 0, stream>>>(We, Wedge_t, 1024, 1024, 1024,
                                                  1024ull*1024, 1024ull*1024);
  transpose_k<<<dim3(32,16,1),  256, 0, stream>>>(Wr, Wrz_t, 2048, 1024, 2048, 0, 0);
  transpose_k<<<dim3(32,16,1),  256, 0, stream>>>(Wz, Wrz_t + 1024ull*2048, 2048, 1024, 2048, 0, 0);
  transpose_k<<<dim3(32,16,1),  256, 0, stream>>>(Wh, Wh_t, 2048, 1024, 2048, 0, 0);
  cat2_kernel<<<8, 256, 0, stream>>>(br, bz, brzv);

  // compress: prop = pose @ W_compress + b_compress  (split-K=8, id%8=ksplit)
  gemm_bf16<0,1><<<dim3(8,8,8), 256, 0, stream>>>(Abf, 25600, Wct, 25600,
      partial, 1024, 921600ull, nullptr, 900, 1024, 25600, 3200,
      nullptr, nullptr, nullptr);
  reduce_compress<<<3600, 256, 0, stream>>>(partial, bc, prop, X);

  // ---- 6 recurrent iterations (last one: scores only) ----
  for (int it = 0; it < 6; it++) {
    attn_kernel<<<dim3(60,7), 256, 0, stream>>>(prop, u_row, u_col, crc, ba, scores);
    if (it == 5) break;
    // msg = prop @ W_edge + b_edge  (bf16 out; 56 col-tiles, id%8=col%8)
    gemm_bf16<4,0><<<dim3(56,8,1), 256, 0, stream>>>(X + 1024, 2048, Wedge_t, 1024,
        (float*)msgb, 7168, 0, be, 900, 7168, 1024, 1024, nullptr, nullptr, nullptr);
    merged_kernel<<<dim3(60,8), 256, 0, stream>>>(msgb, scores, X, Xh);
    // [r|z] = sigmoid(X @ [Wr|Wz] + [br|bz]); r*prop -> Xh right; z -> Zbuf
    gemm_bf16<2,0><<<dim3(16,8,1), 256, 0, stream>>>(X, 2048, Wrz_t, 2048,
        Zbuf, 1024, 0, brzv, 900, 2048, 2048, 2048, nullptr, prop, Xh);
    // h_hat = tanh(Xh @ Wh + bh); prop = (1-z)*prop + z*h_hat -> prop, X right
    gemm_bf16<3,0><<<dim3(8,8,1), 256, 0, stream>>>(Xh, 2048, Wh_t, 2048,
        nullptr, 0, 0, bh, 900, 1024, 2048, 2048, Zbuf, prop, X);
  }

  finalize_kernel<<<60, 256, 0, stream>>>(scores, out);
}

// Round 3
// 747.853 us; speedup vs baseline: 1.6730x; 1.6730x over previous
//
#include <hip/hip_runtime.h>
#include <hip/hip_bf16.h>

typedef unsigned short bf16_t;
typedef __bf16 bf16x8 __attribute__((ext_vector_type(8)));
typedef float f32x4 __attribute__((ext_vector_type(4)));

__device__ __forceinline__ unsigned short f2bf(float x){
  union { __hip_bfloat16 h; unsigned short u; } c;
  c.h = __float2bfloat16(x);
  return c.u;
}
__device__ __forceinline__ float bf2f(bf16_t u){
  union { unsigned short u; __hip_bfloat16 h; } c;
  c.u = u;
  return __bfloat162float(c.h);
}

#define GL2L(g, l) __builtin_amdgcn_global_load_lds( \
    (const __attribute__((address_space(1))) unsigned int*)(g), \
    (__attribute__((address_space(3))) unsigned int*)(l), 16, 0, 0)

// ---------------------------------------------------------------------------
// bf16 MFMA GEMM, 128x128 tile, BK=32, 4 waves (2x2), 4x4 frags of
// v_mfma_f32_16x16x32_bf16.  Bt is [N][K] row-major.
// 4-deep pipelined K-loop: counted vmcnt (8/4/0), ONE raw s_barrier per step,
// stage(t+3) issued right after the barrier (its dest buffer's readers all
// passed the previous barrier).  LDS 16B-unit XOR swizzle c^=(row>>1)&3
// applied to BOTH the GL2L global source and the ds_read address
// (bank-conflict-free: 2 dwords/bank per quarter-wave).
// MAP=0: blockIdx=(col,row,ks) -> id%8 = col%8 (B-panel XCD colocation,
//        launch colTiles%8==0).  MAP=1: blockIdx=(ks,col,row) -> id%8=ks.
// ACT: 0 = f32 store (+ split offset), 4 = bf16 store with bias.
// ---------------------------------------------------------------------------
template<int ACT, int MAP>
__global__ __launch_bounds__(256)
void gemm_bf16(const bf16_t* __restrict__ A, int lda,
               const bf16_t* __restrict__ Bt, int ldb,
               float* __restrict__ C, int ldc, size_t csplit,
               const float* __restrict__ bias,
               int M, int N, int K, int Kchunk)
{
  __shared__ __align__(16) bf16_t As[4][128*32];
  __shared__ __align__(16) bf16_t Bs[4][128*32];
  const int tid = threadIdx.x;
  const int w = tid >> 6, lane = tid & 63;
  const int wm = w >> 1, wn = w & 1;
  const int lr = lane & 15, kq = lane >> 4;
  int bcol, brow, bks;
  if (MAP == 0) { bcol = blockIdx.x; brow = blockIdx.y; bks = blockIdx.z; }
  else          { bks = blockIdx.x;  bcol = blockIdx.y; brow = blockIdx.z; }
  const int gm0 = brow * 128, gn0 = bcol * 128;
  const int k0 = bks * Kchunk;
  const int nt = (min(k0 + Kchunk, K) - k0) >> 5;   // K-tiles (mult of 32)

  // staging: wave w stages rows [w*32, w*32+32); lane l -> row l/4,
  // 16B-unit col (l%4) XOR-swizzled by (row>>1)&3 (same for row+16: 16>>1%4==0)
  const int srow = lane >> 2;
  const int scol = ((lane & 3) ^ ((srow >> 1) & 3)) << 3;   // element offset
  const int am0 = min(gm0 + w*32 + srow,      M-1);
  const int am1 = min(gm0 + w*32 + 16 + srow, M-1);
  const int bn0 = min(gn0 + w*32 + srow,      N-1);
  const int bn1 = min(gn0 + w*32 + 16 + srow, N-1);
  const bf16_t* Ag0 = A  + (size_t)am0*lda + scol;
  const bf16_t* Ag1 = A  + (size_t)am1*lda + scol;
  const bf16_t* Bg0 = Bt + (size_t)bn0*ldb + scol;
  const bf16_t* Bg1 = Bt + (size_t)bn1*ldb + scol;

  auto STAGEF = [&](int t) {
    const int bsel = t & 3;
    const int kk = k0 + (t << 5);
    char* al = (char*)(&As[bsel][0]) + w*2048;
    char* bl = (char*)(&Bs[bsel][0]) + w*2048;
    GL2L(Ag0 + kk, al);
    GL2L(Ag1 + kk, al + 1024);
    GL2L(Bg0 + kk, bl);
    GL2L(Bg1 + kk, bl + 1024);
  };

  STAGEF(0);
  if (nt > 1) STAGEF(1);
  if (nt > 2) STAGEF(2);

  const int kqs = kq ^ ((lr >> 1) & 3);     // swizzled 16B col for frag reads
  f32x4 acc[4][4] = {};

  for (int t = 0; t < nt; ++t) {
    const int rem = nt - t;
    if (rem >= 3)      { asm volatile("s_waitcnt vmcnt(8)" ::: "memory"); }
    else if (rem == 2) { asm volatile("s_waitcnt vmcnt(4)" ::: "memory"); }
    else               { asm volatile("s_waitcnt vmcnt(0)" ::: "memory"); }
    __builtin_amdgcn_s_barrier();           // all waves: tile t in LDS,
    __builtin_amdgcn_sched_barrier(0);      // tile t-1 fully consumed
    if (t + 3 < nt) STAGEF(t + 3);          // overwrites tile t-1's buffer
    const int bsel = t & 3;
    const char* Ab = (const char*)(&As[bsel][0]);
    const char* Bb = (const char*)(&Bs[bsel][0]);
    bf16x8 af[4], bfr[4];
#pragma unroll
    for (int mi = 0; mi < 4; mi++)
      af[mi] = *(const bf16x8*)(Ab + ((wm*64 + mi*16 + lr) << 6) + (kqs << 4));
#pragma unroll
    for (int ni = 0; ni < 4; ni++)
      bfr[ni] = *(const bf16x8*)(Bb + ((wn*64 + ni*16 + lr) << 6) + (kqs << 4));
    __builtin_amdgcn_s_setprio(1);
#pragma unroll
    for (int mi = 0; mi < 4; mi++)
#pragma unroll
      for (int ni = 0; ni < 4; ni++)
        acc[mi][ni] = __builtin_amdgcn_mfma_f32_16x16x32_bf16(af[mi], bfr[ni], acc[mi][ni], 0, 0, 0);
    __builtin_amdgcn_s_setprio(0);
    __builtin_amdgcn_sched_barrier(0);
  }

  // epilogue: D row = kq*4 + i, col = lane&15 per 16x16 frag
#pragma unroll
  for (int mi = 0; mi < 4; mi++) {
#pragma unroll
    for (int ni = 0; ni < 4; ni++) {
      const int col = gn0 + wn*64 + ni*16 + lr;
      const float bv = (ACT == 4) ? bias[col] : 0.f;
#pragma unroll
      for (int i = 0; i < 4; i++) {
        const int row = gm0 + wm*64 + mi*16 + kq*4 + i;
        if (row < M) {
          const float v = acc[mi][ni][i] + bv;
          if (ACT == 4) ((bf16_t*)C)[(size_t)row*ldc + col] = f2bf(v);
          else C[(size_t)bks*csplit + (size_t)row*ldc + col] = v;
        }
      }
    }
  }
}

// sum split-K partials, add bias, write prop f32 + X right half bf16
__global__ void reduce_compress(const float* __restrict__ part, const float* __restrict__ bias,
                                float* __restrict__ prop, bf16_t* __restrict__ xr)
{
  const int idx = blockIdx.x*256 + threadIdx.x;   // < 921600
  const int m = idx >> 10, d = idx & 1023;
  float v = bias[d];
#pragma unroll
  for (int z = 0; z < 8; z++) v += part[(size_t)z*921600 + idx];
  prop[idx] = v;
  xr[(size_t)m*2048 + 1024 + d] = f2bf(v);
}

// RZ split-2 reduce: v = sigmoid(p0+p1+bias). col<1024: Xh_right = bf16(v*prop)
// (the r path); col>=1024: Zbuf = v (the z path).
__global__ void reduce_rz(const float* __restrict__ part, const float* __restrict__ bias,
                          const float* __restrict__ prop, float* __restrict__ Zbuf,
                          bf16_t* __restrict__ Xh)
{
  const int idx = blockIdx.x*256 + threadIdx.x;   // < 1843200
  const int m = idx >> 11, c = idx & 2047;
  float v = part[idx] + part[1843200 + idx] + bias[c];
  v = 1.f / (1.f + __expf(-v));
  if (c < 1024) Xh[(size_t)m*2048 + 1024 + c] = f2bf(v * prop[(size_t)m*1024 + c]);
  else          Zbuf[(size_t)m*1024 + (c - 1024)] = v;
}

// h split-4 reduce: h_hat = tanh(sum+bh); prop = (1-z)*prop + z*h_hat;
// also write X right half bf16.
__global__ void reduce_h(const float* __restrict__ part, const float* __restrict__ bias,
                         const float* __restrict__ Zbuf, float* __restrict__ prop,
                         bf16_t* __restrict__ X)
{
  const int idx = blockIdx.x*256 + threadIdx.x;   // < 921600
  const int m = idx >> 10, d = idx & 1023;
  float v = bias[d];
#pragma unroll
  for (int z = 0; z < 4; z++) v += part[(size_t)z*921600 + idx];
  v = tanhf(v);
  const float zz = Zbuf[idx];
  const float pn = (1.f - zz)*prop[idx] + zz*v;
  prop[idx] = pn;
  X[(size_t)m*2048 + 1024 + d] = f2bf(pn);
}

// u_row[e][h] = sum_d W_edge[e][h][d]*W_att[e][d]; u_col with W_att[e][1024+d]
__global__ void compute_u(const float* __restrict__ We, const float* __restrict__ Wa,
                          float* __restrict__ u_row, float* __restrict__ u_col)
{
  const int w = threadIdx.x >> 6, lane = threadIdx.x & 63;
  const int idx = blockIdx.x*4 + w;               // grid=1792 -> idx<7168
  const int e = idx >> 10, h = idx & 1023;
  const float* wep = We + ((size_t)e*1024 + h)*1024;
  const float* wr  = Wa + (size_t)e*2048;
  const float* wc  = wr + 1024;
  float ar = 0.f, ac = 0.f;
#pragma unroll
  for (int t = 0; t < 16; t++) {
    const float v = wep[lane + 64*t];
    ar += v*wr[lane + 64*t];
    ac += v*wc[lane + 64*t];
  }
  for (int off = 32; off; off >>= 1) { ar += __shfl_down(ar, off); ac += __shfl_down(ac, off); }
  if (lane == 0) { u_row[idx] = ar; u_col[idx] = ac; }
}

// crc[e] = b_edge[e].Wa_row[e], crc[7+e] = b_edge[e].Wa_col[e]
__global__ void crc_kernel(const float* __restrict__ be, const float* __restrict__ Wa,
                           float* __restrict__ crc)
{
  const int w = threadIdx.x >> 6, lane = threadIdx.x & 63;
  for (int idx = w; idx < 14; idx += 4) {
    const int e = idx >> 1, which = idx & 1;
    const float* bp = be + e*1024;
    const float* wp = Wa + (size_t)e*2048 + which*1024;
    float a = 0.f;
#pragma unroll
    for (int t = 0; t < 16; t++) a += bp[lane + 64*t]*wp[lane + 64*t];
    for (int off = 32; off; off >>= 1) a += __shfl_down(a, off);
    if (lane == 0) crc[which*7 + e] = a;
  }
}

// per (b,e): row[n]=prop[b,n,:].u_row[e]; col[n]=prop[b,n,:].u_col[e]
// scores[b,e,i,j] = sigmoid(row[i]+col[j]+b_att[e]+crc_row[e]+crc_col[e])
__global__ void attn_kernel(const float* __restrict__ prop, const float* __restrict__ u_row,
                            const float* __restrict__ u_col, const float* __restrict__ crc,
                            const float* __restrict__ b_att, float* __restrict__ scores)
{
  const int b = blockIdx.x, e = blockIdx.y;
  __shared__ float rowv[15], colv[15];
  const int w = threadIdx.x >> 6, lane = threadIdx.x & 63;
  const float* ur = u_row + (size_t)e*1024;
  const float* uc = u_col + (size_t)e*1024;
  for (int n = w; n < 15; n += 4) {
    const float* pr = prop + (size_t)(b*15 + n)*1024;
    float ar = 0.f, ac = 0.f;
#pragma unroll
    for (int t = 0; t < 16; t++) {
      const float pv = pr[lane + 64*t];
      ar += pv*ur[lane + 64*t];
      ac += pv*uc[lane + 64*t];
    }
    for (int off = 32; off; off >>= 1) { ar += __shfl_down(ar, off); ac += __shfl_down(ac, off); }
    if (lane == 0) { rowv[n] = ar; colv[n] = ac; }
  }
  __syncthreads();
  const float base = b_att[e] + crc[e] + crc[7 + e];
  for (int idx = threadIdx.x; idx < 225; idx += 256) {
    const int i = idx/15, j = idx - i*15;
    const float s = 1.f / (1.f + __expf(-(rowv[i] + colv[j] + base)));
    scores[((size_t)(b*7 + e)*15 + i)*15 + j] = s;
  }
}

// merged[b,i,d] = sum_e sum_j scores[b,e,i,j]*msg[b*15+j, e*1024+d]
// -> X left half AND Xh left half (bf16)
__global__ void merged_kernel(const bf16_t* __restrict__ msg, const float* __restrict__ scores,
                              bf16_t* __restrict__ X, bf16_t* __restrict__ Xh)
{
  const int b = blockIdx.x, c = blockIdx.y;   // c: 128-wide d-chunk, 8 chunks
  __shared__ float ms[15*7*128];              // [j][e][dl]
  __shared__ float sc[1575];                  // [e][i][j]
  for (int q = threadIdx.x; q < 3360; q += 256) {     // 4-wide bf16 loads
    const int idx = q*4;
    const int j = idx / 896;
    const int rem = idx - j*896;
    const int e = rem >> 7, dl = rem & 127;
    const ushort4 v = *(const ushort4*)(msg + (size_t)(b*15 + j)*7168 + e*1024 + c*128 + dl);
    ms[idx]   = bf2f(v.x);
    ms[idx+1] = bf2f(v.y);
    ms[idx+2] = bf2f(v.z);
    ms[idx+3] = bf2f(v.w);
  }
  for (int idx = threadIdx.x; idx < 1575; idx += 256)
    sc[idx] = scores[(size_t)b*1575 + idx];
  __syncthreads();
  for (int oi = threadIdx.x; oi < 1920; oi += 256) {
    const int i = oi >> 7, dl = oi & 127;
    float acc = 0.f;
#pragma unroll
    for (int e = 0; e < 7; e++)
#pragma unroll
      for (int j = 0; j < 15; j++)
        acc += sc[(e*15 + i)*15 + j] * ms[j*896 + e*128 + dl];
    const bf16_t o = f2bf(acc);
    X [(size_t)(b*15 + i)*2048 + c*128 + dl] = o;
    Xh[(size_t)(b*15 + i)*2048 + c*128 + dl] = o;
  }
}

// 64x64-tile transpose f32 -> bf16: out[c][r] = in[r][c]  (dims %64 == 0)
__global__ void transpose_k(const float* __restrict__ in, bf16_t* __restrict__ out,
                            int R, int C, int out_ld, size_t in_batch, size_t out_batch)
{
  __shared__ float t[64][65];
  in  += (size_t)blockIdx.z * in_batch;
  out += (size_t)blockIdx.z * out_batch;
  const int r0 = blockIdx.x*64, c0 = blockIdx.y*64;
  const int tc = threadIdx.x & 63, tr = threadIdx.x >> 6;
#pragma unroll
  for (int i = 0; i < 16; i++) {
    const int r = tr*16 + i;
    t[r][tc] = in[(size_t)(r0 + r)*C + c0 + tc];
  }
  __syncthreads();
#pragma unroll
  for (int i = 0; i < 16; i++) {
    const int rr = tr*16 + i;
    out[(size_t)(c0 + rr)*out_ld + r0 + tc] = f2bf(t[tc][rr]);
  }
}

__global__ void cast_f32_bf16(const float4* __restrict__ in, ushort4* __restrict__ out, int n4)
{
  int i = blockIdx.x*256 + threadIdx.x;
  const int stride = gridDim.x*256;
  for (; i < n4; i += stride) {
    const float4 v = in[i];
    out[i] = make_ushort4(f2bf(v.x), f2bf(v.y), f2bf(v.z), f2bf(v.w));
  }
}

__global__ void cat2_kernel(const float* __restrict__ a, const float* __restrict__ b,
                            float* __restrict__ o)
{
  const int i = blockIdx.x*256 + threadIdx.x;
  if (i < 1024) o[i] = a[i];
  else if (i < 2048) o[i] = b[i - 1024];
}

// final outputs from last-iteration scores
__global__ void finalize_kernel(const float* __restrict__ scores, float* __restrict__ out)
{
  const int b = blockIdx.x;   // 0..59
  __shared__ float sc[1575];
  __shared__ float act[105];
  __shared__ float asum[15];
  __shared__ float t2[7];
  for (int idx = threadIdx.x; idx < 1575; idx += 256)
    sc[idx] = scores[(size_t)b*1575 + idx];
  __syncthreads();
  for (int idx = threadIdx.x; idx < 105; idx += 256) {
    const int i = idx/7, e = idx - i*7;
    float a = 0.f;
#pragma unroll
    for (int j = 0; j < 15; j++)
      a += (1.f - sc[i*15 + j]) * sc[(e*15 + i)*15 + j];
    act[idx] = a;
    out[(size_t)b*105 + idx] = a;
  }
  for (int idx = threadIdx.x; idx < 225; idx += 256) {
    const int i = idx/15, j = idx - i*15;
    out[6660 + (size_t)b*225 + idx] = 1.f - sc[i*15 + j];
  }
  if (threadIdx.x < 15) {
    const int i = threadIdx.x;
    float s = 0.f;
#pragma unroll
    for (int j = 0; j < 15; j++) s += 1.f - sc[i*15 + j];
    asum[i] = s;
  }
  __syncthreads();
  if (threadIdx.x < 7) {
    const int e = threadIdx.x;
    float t = 0.f;
#pragma unroll
    for (int i = 0; i < 15; i++) t += act[i*7 + e]*asum[i];
    t2[e] = t;
  }
  __syncthreads();
  if (threadIdx.x == 0) {
    float mx = -1e30f;
    for (int e = 1; e < 7; e++) mx = fmaxf(mx, t2[e]);
    float s = 0.f, ex[6];
    for (int e = 1; e < 7; e++) { ex[e-1] = __expf(t2[e] - mx); s += ex[e-1]; }
    for (int e = 1; e < 7; e++) out[6300 + (size_t)b*6 + (e-1)] = ex[e-1]/s;
  }
}

extern "C" void kernel_launch(void* const* d_in, const int* in_sizes, int n_in,
                              void* d_out, int out_size, void* d_ws, size_t ws_size,
                              hipStream_t stream)
{
  const float* pose = (const float*)d_in[0];
  const float* Wc   = (const float*)d_in[1];
  const float* bc   = (const float*)d_in[2];
  const float* We   = (const float*)d_in[3];
  const float* be   = (const float*)d_in[4];
  const float* Wa   = (const float*)d_in[5];
  const float* ba   = (const float*)d_in[6];
  const float* Wr   = (const float*)d_in[7];
  const float* br   = (const float*)d_in[8];
  const float* Wz   = (const float*)d_in[9];
  const float* bz   = (const float*)d_in[10];
  const float* Wh   = (const float*)d_in[11];
  const float* bh   = (const float*)d_in[12];
  float* out = (float*)d_out;

  // ---- workspace carving ----
  char* p = (char*)d_ws;
  auto alloc = [&](size_t b) { char* r = p; p += (b + 255) & ~(size_t)255; return r; };
  bf16_t* Wedge_t = (bf16_t*)alloc(7168ull*1024*2);   // [e*1024+d][h]
  bf16_t* Wrz_t   = (bf16_t*)alloc(2048ull*2048*2);   // [n][k]
  bf16_t* Wh_t    = (bf16_t*)alloc(1024ull*2048*2);   // [n][k]
  bf16_t* X       = (bf16_t*)alloc(900ull*2048*2);    // [merged | prop] bf16
  float*  prop    = (float*) alloc(900ull*1024*4);    // f32 master state
  float*  scores  = (float*) alloc(60ull*7*15*15*4);
  float*  u_row   = (float*) alloc(7168*4);
  float*  u_col   = (float*) alloc(7168*4);
  float*  crc     = (float*) alloc(64);
  float*  brzv    = (float*) alloc(2048*4);
  // phase-union region:
  // phase1 (compress): Abf(46.08) + Wct(52.43) + partial(29.49) = 128 MB
  // phase2 (iters): msgb 12.9 | Zbuf 3.69 | Xh 3.69 | partRZ 29.5 | partH 14.7
  char* r1 = alloc(128000000ull);
  bf16_t* Abf     = (bf16_t*)r1;
  bf16_t* Wct     = (bf16_t*)(r1 + 46080000ull);
  float*  partial = (float*) (r1 + 46080000ull + 52428800ull);
  bf16_t* msgb    = (bf16_t*)r1;
  float*  Zbuf    = (float*) (r1 + 12902400ull);
  bf16_t* Xh      = (bf16_t*)(r1 + 16588800ull);
  float*  partRZ  = (float*) (r1 + 20275200ull);      // 2 x 900 x 2048 f32
  float*  partH   = (float*) (r1 + 49766400ull);      // 4 x 900 x 1024 f32

  // ---- precompute ----
  compute_u<<<1792, 256, 0, stream>>>(We, Wa, u_row, u_col);
  crc_kernel<<<1, 256, 0, stream>>>(be, Wa, crc);
  cast_f32_bf16<<<2048, 256, 0, stream>>>((const float4*)pose, (ushort4*)Abf, 23040000/4);
  transpose_k<<<dim3(400,16,1), 256, 0, stream>>>(Wc, Wct, 25600, 1024, 25600, 0, 0);
  transpose_k<<<dim3(16,16,7),  256, 0, stream>>>(We, Wedge_t, 1024, 1024, 1024,
                                                  1024ull*1024, 1024ull*1024);
  transpose_k<<<dim3(32,16,1),  256, 0, stream>>>(Wr, Wrz_t, 2048, 1024, 2048, 0, 0);
  transpose_k<<<dim3(32,16,1),  256, 0, stream>>>(Wz, Wrz_t + 1024ull*2048, 2048, 1024, 2048, 0, 0);
  transpose_k<<<dim3(32,16,1),  256, 0, stream>>>(Wh, Wh_t, 2048, 1024, 2048, 0, 0);
  cat2_kernel<<<8, 256, 0, stream>>>(br, bz, brzv);

  // compress: prop = pose @ W_compress + b_compress  (split-K=8, id%8=ksplit)
  gemm_bf16<0,1><<<dim3(8,8,8), 256, 0, stream>>>(Abf, 25600, Wct, 25600,
      partial, 1024, 921600ull, nullptr, 900, 1024, 25600, 3200);
  reduce_compress<<<3600, 256, 0, stream>>>(partial, bc, prop, X);

  // ---- 6 recurrent iterations (last one: scores only) ----
  for (int it = 0; it < 6; it++) {
    attn_kernel<<<dim3(60,7), 256, 0, stream>>>(prop, u_row, u_col, crc, ba, scores);
    if (it == 5) break;
    // msg = prop @ W_edge + b_edge  (bf16 out; 56 col-tiles, id%8=col%8)
    gemm_bf16<4,0><<<dim3(56,8,1), 256, 0, stream>>>(X + 1024, 2048, Wedge_t, 1024,
        (float*)msgb, 7168, 0, be, 900, 7168, 1024, 1024);
    merged_kernel<<<dim3(60,8), 256, 0, stream>>>(msgb, scores, X, Xh);
    // [r|z] partials = X @ [Wr|Wz]   (split-K=2 -> 256 blocks)
    gemm_bf16<0,0><<<dim3(16,8,2), 256, 0, stream>>>(X, 2048, Wrz_t, 2048,
        partRZ, 2048, 1843200ull, nullptr, 900, 2048, 2048, 1024);
    reduce_rz<<<7200, 256, 0, stream>>>(partRZ, brzv, prop, Zbuf, Xh);
    // h partials = Xh @ Wh  (split-K=4 -> 256 blocks)
    gemm_bf16<0,0><<<dim3(8,8,4), 256, 0, stream>>>(Xh, 2048, Wh_t, 2048,
        partH, 1024, 921600ull, nullptr, 900, 1024, 2048, 512);
    reduce_h<<<3600, 256, 0, stream>>>(partH, bh, Zbuf, prop, X);
  }

  finalize_kernel<<<60, 256, 0, stream>>>(scores, out);
}